// Round 4
// baseline (741.190 us; speedup 1.0000x reference)
//
#include <hip/hip_runtime.h>

typedef float f32x4 __attribute__((ext_vector_type(4)));
typedef __bf16 bf16x4 __attribute__((ext_vector_type(4)));
typedef __bf16 bf16x8 __attribute__((ext_vector_type(8)));

#define DEVI static __device__ __forceinline__

DEVI f32x4 mfma16(bf16x8 a, bf16x8 b, f32x4 c) {
    return __builtin_amdgcn_mfma_f32_16x16x32_bf16(a, b, c, 0, 0, 0);
}

union F8 { bf16x8 v; bf16x4 h[2]; };

DEVI bf16x8 ld8_lds(const __bf16* p) {   // 16B fragment from LDS (two b64 reads)
    F8 f;
    f.h[0] = *(const bf16x4*)p;
    f.h[1] = *(const bf16x4*)(p + 4);
    return f.v;
}
// 8 consecutive fp32 from global -> bf16x8 fragment
DEVI bf16x8 ldf8(const float* p) {
    f32x4 a = *(const f32x4*)p;
    f32x4 b = *(const f32x4*)(p + 4);
    F8 f;
#pragma unroll
    for (int j = 0; j < 4; ++j) {
        f.h[0][j] = (__bf16)a[j];
        f.h[1][j] = (__bf16)b[j];
    }
    return f.v;
}

// ---------------------------------------------------------------------------
// Fully fused shifted-window attention block.  1 block = 1 window (2048 blks).
// fp32 I/O, bf16 MFMA internally.  No workspace.
// ---------------------------------------------------------------------------
__global__ __launch_bounds__(256) void k_swin(
    const float* __restrict__ x,     // [32,56,56,256] fp32
    const float* __restrict__ wqkv,  // [768,256]
    const float* __restrict__ bqkv,  // [768]
    const float* __restrict__ btab,  // [169,8]
    const float* __restrict__ wp,    // [256,256]
    const float* __restrict__ pbias, // [256]
    float* __restrict__ out)         // [32,56,56,256] fp32
{
    // ---- LDS carve (64,304 B static, all offsets 16B-aligned) ----
    __shared__ __align__(16) unsigned char smem[64304];
    __bf16* xw = (__bf16*)(smem);             // [49][260]  tokens (bf16)
    __bf16* Q  = (__bf16*)(smem + 25488);     // [2][64][36]
    __bf16* K  = (__bf16*)(smem + 34704);     // [2][64][36]
    __bf16* VT = (__bf16*)(smem + 43920);     // [2][32][68] transposed V
    __bf16* P  = (__bf16*)(smem + 52624);     // [64][68]
    __bf16* tb = (__bf16*)(smem + 61328);     // [8][170]   bias table, head-major
    unsigned* tinfo = (unsigned*)(smem + 64048); // [64] packed i|j<<8|region<<16
    // overlay (live only after the head-pair loop):
    __bf16* cb = (__bf16*)(smem + 25488);     // [49][260] ctx  (over Q/K/VT)

    const int tid = threadIdx.x;
    const int wid = tid >> 6;
    const int lane = tid & 63;
    const int li = lane & 15;
    const int q4 = lane >> 4;
    const int blk = blockIdx.x;
    const int b = blk >> 6, wi = blk & 63;
    const int wh = wi >> 3, ww = wi & 7;

    // ---- stage shifted window (fp32 -> bf16):
    for (int c = tid; c < 49 * 32; c += 256) {
        int tok = c >> 5, part = c & 31;
        int i = tok / 7, j = tok - 7 * i;
        int r = wh * 7 + i + 3;  if (r >= 56) r -= 56;
        int cc = ww * 7 + j + 3; if (cc >= 56) cc -= 56;
        F8 f = { ldf8(x + (((size_t)(b * 56 + r) * 56 + cc) << 8) + (part << 3)) };
        __bf16* dst = xw + tok * 260 + (part << 3);
        *(bf16x4*)dst = f.h[0];
        *(bf16x4*)(dst + 4) = f.h[1];
    }
    for (int c = tid; c < 169 * 8; c += 256) {       // bias table, transposed
        int idx = c >> 3, h = c & 7;
        tb[h * 170 + idx] = (__bf16)btab[c];
    }
    if (tid < 64) {                                  // closed-form swin region ids
        int tok = tid;
        if (tok < 49) {
            int i = tok / 7, j = tok - 7 * i;
            unsigned rh = (wh == 7) ? (i < 4 ? 1u : 2u) : 0u;
            unsigned rw = (ww == 7) ? (j < 4 ? 1u : 2u) : 0u;
            tinfo[tok] = (unsigned)i | ((unsigned)j << 8) | ((rh * 3u + rw) << 16);
        } else {
            tinfo[tok] = 255u << 16;
        }
    }
    __syncthreads();

    const f32x4 zf = {0.f, 0.f, 0.f, 0.f};
    f32x4 osv[4][2][2];                  // per-lane ctx fragments [p][hl][nt]

#pragma unroll
    for (int p = 0; p < 4; ++p) {        // head pairs (2p, 2p+1)
        // ---------------- QKV GEMM: wave owns 3 of 12 channel-tiles ----------
        f32x4 acc[3][4];
#pragma unroll
        for (int s = 0; s < 3; ++s)
#pragma unroll
            for (int mt = 0; mt < 4; ++mt) acc[s][mt] = zf;

        const int tbase = 3 * wid;
        const float* bp[3];
#pragma unroll
        for (int s = 0; s < 3; ++s) {
            int t = tbase + s, grp = t >> 2, tt = t & 3;
            bp[s] = wqkv + (size_t)(grp * 256 + p * 64 + tt * 16 + li) * 256;
        }
#pragma unroll
        for (int kc = 0; kc < 8; ++kc) {
            bf16x8 a[4];
#pragma unroll
            for (int mt = 0; mt < 4; ++mt) {
                int row = 16 * mt + li; if (row > 48) row = 48;   // M-pad clamp
                a[mt] = ld8_lds(xw + row * 260 + kc * 32 + q4 * 8);
            }
#pragma unroll
            for (int s = 0; s < 3; ++s) {
                bf16x8 bb = ldf8(bp[s] + kc * 32 + q4 * 8);
#pragma unroll
                for (int mt = 0; mt < 4; ++mt)
                    acc[s][mt] = mfma16(a[mt], bb, acc[s][mt]);
            }
        }
        __syncthreads();   // prior iteration's attention reads of Q/K/VT done
        // ---- epilogue: +bias, scale q, scatter to Q/K/VT
#pragma unroll
        for (int s = 0; s < 3; ++s) {
            int t = tbase + s, grp = t >> 2, tt = t & 3;
            int hl = tt >> 1, d = (tt & 1) * 16 + li;
            float bias = bqkv[grp * 256 + p * 64 + tt * 16 + li];
#pragma unroll
            for (int mt = 0; mt < 4; ++mt)
#pragma unroll
                for (int reg = 0; reg < 4; ++reg) {
                    int row = 16 * mt + 4 * q4 + reg;
                    float v = acc[s][mt][reg] + bias;
                    if (grp == 0)
                        Q[(hl * 64 + row) * 36 + d] = (__bf16)(v * 0.17677669529663687f);
                    else if (grp == 1)
                        K[(hl * 64 + row) * 36 + d] = (__bf16)v;
                    else
                        VT[hl * 2176 + d * 68 + row] = (__bf16)v;
                }
        }
        __syncthreads();

        // ---------------- attention: wave owns token rows [16*wid, 16*wid+16)
#pragma unroll
        for (int hl = 0; hl < 2; ++hl) {
            const int h = 2 * p + hl;
            bf16x8 qf = ld8_lds(Q + (hl * 64 + 16 * wid + li) * 36 + q4 * 8);
            f32x4 s4[4];
#pragma unroll
            for (int nt = 0; nt < 4; ++nt) {
                bf16x8 kf = ld8_lds(K + (hl * 64 + 16 * nt + li) * 36 + q4 * 8);
                s4[nt] = mfma16(qf, kf, zf);
            }
            unsigned inM[4];
#pragma unroll
            for (int nt = 0; nt < 4; ++nt) inM[nt] = tinfo[li + 16 * nt];
#pragma unroll
            for (int reg = 0; reg < 4; ++reg) {
                int n = 16 * wid + 4 * q4 + reg;
                unsigned inN = tinfo[n];
                float v[4];
#pragma unroll
                for (int nt = 0; nt < 4; ++nt) {
                    int di = (int)(inN & 255) - (int)(inM[nt] & 255);
                    int dj = (int)((inN >> 8) & 255) - (int)((inM[nt] >> 8) & 255);
                    int idx = (di + 6) * 13 + (dj + 6);
                    float bias = (float)tb[h * 170 + idx];
                    float msk = ((inN ^ inM[nt]) >> 16) ? -100.f : 0.f;
                    v[nt] = s4[nt][reg] + bias + msk;
                }
                if (li > 0) v[3] = -30000.f;            // mask cols m >= 49
                float mx = fmaxf(fmaxf(v[0], v[1]), fmaxf(v[2], v[3]));
                mx = fmaxf(mx, __shfl_xor(mx, 1, 16));
                mx = fmaxf(mx, __shfl_xor(mx, 2, 16));
                mx = fmaxf(mx, __shfl_xor(mx, 4, 16));
                mx = fmaxf(mx, __shfl_xor(mx, 8, 16));
                float sum = 0.f;
#pragma unroll
                for (int nt = 0; nt < 4; ++nt) { v[nt] = __expf(v[nt] - mx); sum += v[nt]; }
                sum += __shfl_xor(sum, 1, 16);
                sum += __shfl_xor(sum, 2, 16);
                sum += __shfl_xor(sum, 4, 16);
                sum += __shfl_xor(sum, 8, 16);
                float inv = 1.0f / sum;
#pragma unroll
                for (int nt = 0; nt < 4; ++nt)
                    P[n * 68 + li + 16 * nt] = (__bf16)(v[nt] * inv);
            }
            // PV (wave-private P rows; VT synced above)
            f32x4 o0 = zf, o1 = zf;
#pragma unroll
            for (int kt = 0; kt < 2; ++kt) {
                bf16x8 pf = ld8_lds(P + (16 * wid + li) * 68 + kt * 32 + q4 * 8);
                bf16x8 vf0 = ld8_lds(VT + hl * 2176 + (li) * 68 + kt * 32 + q4 * 8);
                bf16x8 vf1 = ld8_lds(VT + hl * 2176 + (16 + li) * 68 + kt * 32 + q4 * 8);
                o0 = mfma16(pf, vf0, o0);
                o1 = mfma16(pf, vf1, o1);
            }
            osv[p][hl][0] = o0;
            osv[p][hl][1] = o1;
        }
        __syncthreads();   // attention done before next p's epilogue overwrite
    }

    // ---- ctx registers -> cb (overlays dead Q/K/VT) ----
#pragma unroll
    for (int p = 0; p < 4; ++p)
#pragma unroll
        for (int hl = 0; hl < 2; ++hl)
#pragma unroll
            for (int nt = 0; nt < 2; ++nt)
#pragma unroll
                for (int reg = 0; reg < 4; ++reg) {
                    int n = 16 * wid + 4 * q4 + reg;
                    if (n < 49)
                        cb[n * 260 + (2 * p + hl) * 32 + 16 * nt + li] =
                            (__bf16)osv[p][hl][nt][reg];
                }
    __syncthreads();

    // ---- output projection: C[49x256] = cb[49x256] @ wp^T + pbias ----
    f32x4 pacc[4][4];
#pragma unroll
    for (int mt = 0; mt < 4; ++mt)
#pragma unroll
        for (int nt = 0; nt < 4; ++nt) pacc[mt][nt] = zf;

#pragma unroll
    for (int kc = 0; kc < 8; ++kc) {
        bf16x8 a[4];
#pragma unroll
        for (int mt = 0; mt < 4; ++mt) {
            int row = 16 * mt + li; if (row > 48) row = 48;
            a[mt] = ld8_lds(cb + row * 260 + kc * 32 + q4 * 8);
        }
#pragma unroll
        for (int nt = 0; nt < 4; ++nt) {
            int o = 64 * wid + 16 * nt + li;
            bf16x8 bb = ldf8(wp + (size_t)o * 256 + kc * 32 + q4 * 8);
#pragma unroll
            for (int mt = 0; mt < 4; ++mt)
                pacc[mt][nt] = mfma16(a[mt], bb, pacc[mt][nt]);
        }
    }

    // ---- epilogue: bias + direct fp32 scatter (un-window + roll-back) ----
#pragma unroll
    for (int nt = 0; nt < 4; ++nt) {
        int o = 64 * wid + 16 * nt + li;
        float bias = pbias[o];
#pragma unroll
        for (int mt = 0; mt < 4; ++mt)
#pragma unroll
            for (int reg = 0; reg < 4; ++reg) {
                int n = 16 * mt + 4 * q4 + reg;
                if (n < 49) {
                    int i = n / 7, j = n - 7 * i;
                    int r = wh * 7 + i + 3;  if (r >= 56) r -= 56;
                    int cc = ww * 7 + j + 3; if (cc >= 56) cc -= 56;
                    out[(((size_t)(b * 56 + r) * 56 + cc) << 8) + o] =
                        pacc[mt][nt][reg] + bias;
                }
            }
    }
}

extern "C" void kernel_launch(void* const* d_in, const int* in_sizes, int n_in,
                              void* d_out, int out_size, void* d_ws, size_t ws_size,
                              hipStream_t stream) {
    const float* x    = (const float*)d_in[0];
    const float* wqkv = (const float*)d_in[1];
    const float* bqkv = (const float*)d_in[2];
    const float* wp   = (const float*)d_in[3];
    const float* pb   = (const float*)d_in[4];
    const float* btab = (const float*)d_in[5];
    float* out = (float*)d_out;

    k_swin<<<2048, 256, 0, stream>>>(x, wqkv, bqkv, btab, wp, pb, out);
}

// Round 5
// 640.721 us; speedup vs baseline: 1.1568x; 1.1568x over previous
//
#include <hip/hip_runtime.h>

typedef float f32x4 __attribute__((ext_vector_type(4)));
typedef __bf16 bf16x4 __attribute__((ext_vector_type(4)));
typedef __bf16 bf16x8 __attribute__((ext_vector_type(8)));

#define DEVI static __device__ __forceinline__

DEVI f32x4 mfma16(bf16x8 a, bf16x8 b, f32x4 c) {
    return __builtin_amdgcn_mfma_f32_16x16x32_bf16(a, b, c, 0, 0, 0);
}

union F8 { bf16x8 v; bf16x4 h[2]; };

DEVI bf16x8 ld8_lds(const __bf16* p) {   // 16B fragment from LDS (two b64 reads)
    F8 f;
    f.h[0] = *(const bf16x4*)p;
    f.h[1] = *(const bf16x4*)(p + 4);
    return f.v;
}
DEVI bf16x8 ld8_gb(const __bf16* p) { return *(const bf16x8*)p; }  // 16B global
DEVI bf16x8 ldf8(const float* p) {       // 8 fp32 -> bf16x8
    f32x4 a = *(const f32x4*)p;
    f32x4 b = *(const f32x4*)(p + 4);
    F8 f;
#pragma unroll
    for (int j = 0; j < 4; ++j) {
        f.h[0][j] = (__bf16)a[j];
        f.h[1][j] = (__bf16)b[j];
    }
    return f.v;
}
DEVI bf16x4 pk4(f32x4 v) {
    bf16x4 r;
#pragma unroll
    for (int j = 0; j < 4; ++j) r[j] = (__bf16)v[j];
    return r;
}

// ---- pre-kernel: weights fp32 -> bf16 into workspace (runs every launch) ----
__global__ __launch_bounds__(256) void k_w2bf(const float* __restrict__ wqkv,
                                              const float* __restrict__ wp,
                                              __bf16* __restrict__ o) {
    int i = blockIdx.x * 256 + threadIdx.x;        // grid covers 262144
    if (i < 196608) o[i] = (__bf16)wqkv[i];
    else            o[i] = (__bf16)wp[i - 196608];
}

// ---------------------------------------------------------------------------
// Fused shifted-window attention block.  1 block = 1 window, 8 waves.
// ---------------------------------------------------------------------------
__global__ __launch_bounds__(512, 4) void k_swin(
    const float* __restrict__ x,      // [32,56,56,256] fp32
    const __bf16* __restrict__ wqkvb, // [768,256] bf16 (ws)
    const float* __restrict__ bqkv,   // [768]
    const float* __restrict__ btab,   // [169,8]
    const __bf16* __restrict__ wpb,   // [256,256] bf16 (ws)
    const float* __restrict__ pbias,  // [256]
    float* __restrict__ out)          // [32,56,56,256] fp32
{
    // ---- LDS carve (64,304 B static) ----
    __shared__ __align__(16) unsigned char smem[64304];
    __bf16* xw = (__bf16*)(smem);             // [49][260]
    __bf16* Q  = (__bf16*)(smem + 25488);     // [2][64][36]
    __bf16* K  = (__bf16*)(smem + 34704);     // [2][64][36]
    __bf16* VT = (__bf16*)(smem + 43920);     // [2][32][68]
    __bf16* P  = (__bf16*)(smem + 52624);     // [64][68]
    __bf16* tb = (__bf16*)(smem + 61328);     // [8][170]
    unsigned* tinfo = (unsigned*)(smem + 64048); // [64]
    __bf16* cb = (__bf16*)(smem + 25488);     // [49][260] ctx overlay (over Q/K/VT)

    const int tid = threadIdx.x;
    const int wid = tid >> 6;        // 0..7
    const int lane = tid & 63;
    const int li = lane & 15;
    const int q4 = lane >> 4;
    const int blk = blockIdx.x;
    const int b = blk >> 6, wi = blk & 63;
    const int wh = wi >> 3, ww = wi & 7;

    // ---- stage shifted window (fp32 -> bf16) ----
    for (int c = tid; c < 49 * 32; c += 512) {
        int tok = c >> 5, part = c & 31;
        int i = tok / 7, j = tok - 7 * i;
        int r = wh * 7 + i + 3;  if (r >= 56) r -= 56;
        int cc = ww * 7 + j + 3; if (cc >= 56) cc -= 56;
        F8 f; f.v = ldf8(x + (((size_t)(b * 56 + r) * 56 + cc) << 8) + (part << 3));
        __bf16* dst = xw + tok * 260 + (part << 3);
        *(bf16x4*)dst = f.h[0];
        *(bf16x4*)(dst + 4) = f.h[1];
    }
    for (int c = tid; c < 169 * 8; c += 512) {       // bias table, transposed
        int idx = c >> 3, h = c & 7;
        tb[h * 170 + idx] = (__bf16)btab[c];
    }
    if (tid < 64) {
        int tok = tid;
        if (tok < 49) {
            int i = tok / 7, j = tok - 7 * i;
            unsigned rh = (wh == 7) ? (i < 4 ? 1u : 2u) : 0u;
            unsigned rw = (ww == 7) ? (j < 4 ? 1u : 2u) : 0u;
            tinfo[tok] = (unsigned)i | ((unsigned)j << 8) | ((rh * 3u + rw) << 16);
        } else {
            tinfo[tok] = 255u << 16;
        }
    }
    __syncthreads();

    const f32x4 zf = {0.f, 0.f, 0.f, 0.f};
    bf16x4 osv[4][2][2];             // ctx fragments (bf16), waves 0-3 only
    const int cg = wid & 3, mh = wid >> 2;   // QKV GEMM split
    const int tbase = 3 * cg;

    for (int p = 0; p < 4; ++p) {    // head pairs (2p, 2p+1)
        // -------- QKV GEMM: 8 waves, wave = (cg: 3 col-tiles, mh: 32 rows) ----
        f32x4 acc[3][2];
#pragma unroll
        for (int s = 0; s < 3; ++s)
#pragma unroll
            for (int mt = 0; mt < 2; ++mt) acc[s][mt] = zf;

        const __bf16* bp[3];
#pragma unroll
        for (int s = 0; s < 3; ++s) {
            int t = tbase + s, grp = t >> 2, tt = t & 3;
            bp[s] = wqkvb + (size_t)(grp * 256 + p * 64 + tt * 16 + li) * 256;
        }
#pragma unroll
        for (int kc = 0; kc < 8; ++kc) {
            bf16x8 a[2];
#pragma unroll
            for (int mt = 0; mt < 2; ++mt) {
                int row = 32 * mh + 16 * mt + li; if (row > 48) row = 48;
                a[mt] = ld8_lds(xw + row * 260 + kc * 32 + q4 * 8);
            }
#pragma unroll
            for (int s = 0; s < 3; ++s) {
                bf16x8 bb = ld8_gb(bp[s] + kc * 32 + q4 * 8);
#pragma unroll
                for (int mt = 0; mt < 2; ++mt)
                    acc[s][mt] = mfma16(a[mt], bb, acc[s][mt]);
            }
        }
        __syncthreads();   // prior iteration's attention reads of Q/K/VT done
        // -------- epilogue: +bias, scale q, scatter to Q/K/VT --------
#pragma unroll
        for (int s = 0; s < 3; ++s) {
            int t = tbase + s, grp = t >> 2, tt = t & 3;
            int hl = tt >> 1, d = (tt & 1) * 16 + li;
            float bias = bqkv[grp * 256 + p * 64 + tt * 16 + li];
#pragma unroll
            for (int mt = 0; mt < 2; ++mt) {
                int row0 = 32 * mh + 16 * mt + 4 * q4;
                if (grp == 2) {                       // V^T: 4 rows -> one 8B store
                    bf16x4 vv;
#pragma unroll
                    for (int reg = 0; reg < 4; ++reg)
                        vv[reg] = (__bf16)(acc[s][mt][reg] + bias);
                    *(bf16x4*)(VT + hl * 2176 + d * 68 + row0) = vv;
                } else if (grp == 0) {
#pragma unroll
                    for (int reg = 0; reg < 4; ++reg)
                        Q[(hl * 64 + row0 + reg) * 36 + d] =
                            (__bf16)((acc[s][mt][reg] + bias) * 0.17677669529663687f);
                } else {
#pragma unroll
                    for (int reg = 0; reg < 4; ++reg)
                        K[(hl * 64 + row0 + reg) * 36 + d] =
                            (__bf16)(acc[s][mt][reg] + bias);
                }
            }
        }
        __syncthreads();

        // -------- attention: waves 0-3, wave owns rows [16*wid, 16*wid+16) ----
        if (wid < 4) {
#pragma unroll
            for (int hl = 0; hl < 2; ++hl) {
                const int h = 2 * p + hl;
                bf16x8 qf = ld8_lds(Q + (hl * 64 + 16 * wid + li) * 36 + q4 * 8);
                f32x4 s4[4];
#pragma unroll
                for (int nt = 0; nt < 4; ++nt) {
                    bf16x8 kf = ld8_lds(K + (hl * 64 + 16 * nt + li) * 36 + q4 * 8);
                    s4[nt] = mfma16(qf, kf, zf);
                }
                unsigned inM[4];
#pragma unroll
                for (int nt = 0; nt < 4; ++nt) inM[nt] = tinfo[li + 16 * nt];
#pragma unroll
                for (int reg = 0; reg < 4; ++reg) {
                    int n = 16 * wid + 4 * q4 + reg;
                    unsigned inN = tinfo[n];
                    float v[4];
#pragma unroll
                    for (int nt = 0; nt < 4; ++nt) {
                        int di = (int)(inN & 255) - (int)(inM[nt] & 255);
                        int dj = (int)((inN >> 8) & 255) - (int)((inM[nt] >> 8) & 255);
                        int idx = (di + 6) * 13 + (dj + 6);
                        float bias = (float)tb[h * 170 + idx];
                        float msk = ((inN ^ inM[nt]) >> 16) ? -100.f : 0.f;
                        v[nt] = s4[nt][reg] + bias + msk;
                    }
                    if (li > 0) v[3] = -30000.f;        // mask cols m >= 49
                    float mx = fmaxf(fmaxf(v[0], v[1]), fmaxf(v[2], v[3]));
                    mx = fmaxf(mx, __shfl_xor(mx, 1, 16));
                    mx = fmaxf(mx, __shfl_xor(mx, 2, 16));
                    mx = fmaxf(mx, __shfl_xor(mx, 4, 16));
                    mx = fmaxf(mx, __shfl_xor(mx, 8, 16));
                    float sum = 0.f;
#pragma unroll
                    for (int nt = 0; nt < 4; ++nt) { v[nt] = __expf(v[nt] - mx); sum += v[nt]; }
                    sum += __shfl_xor(sum, 1, 16);
                    sum += __shfl_xor(sum, 2, 16);
                    sum += __shfl_xor(sum, 4, 16);
                    sum += __shfl_xor(sum, 8, 16);
                    float inv = 1.0f / sum;
#pragma unroll
                    for (int nt = 0; nt < 4; ++nt)
                        P[n * 68 + li + 16 * nt] = (__bf16)(v[nt] * inv);
                }
                // PV (wave-private P rows)
                f32x4 o0 = zf, o1 = zf;
#pragma unroll
                for (int kt = 0; kt < 2; ++kt) {
                    bf16x8 pf = ld8_lds(P + (16 * wid + li) * 68 + kt * 32 + q4 * 8);
                    bf16x8 vf0 = ld8_lds(VT + hl * 2176 + (li) * 68 + kt * 32 + q4 * 8);
                    bf16x8 vf1 = ld8_lds(VT + hl * 2176 + (16 + li) * 68 + kt * 32 + q4 * 8);
                    o0 = mfma16(pf, vf0, o0);
                    o1 = mfma16(pf, vf1, o1);
                }
                osv[p][hl][0] = pk4(o0);
                osv[p][hl][1] = pk4(o1);
            }
        }
        __syncthreads();   // attention done before next p's epilogue overwrite
    }

    // ---- ctx fragments -> cb (overlays dead Q/K/VT) ----
    if (wid < 4) {
#pragma unroll
        for (int p = 0; p < 4; ++p)
#pragma unroll
            for (int hl = 0; hl < 2; ++hl)
#pragma unroll
                for (int nt = 0; nt < 2; ++nt)
#pragma unroll
                    for (int reg = 0; reg < 4; ++reg) {
                        int n = 16 * wid + 4 * q4 + reg;
                        if (n < 49)
                            cb[n * 260 + (2 * p + hl) * 32 + 16 * nt + li] =
                                osv[p][hl][nt][reg];
                    }
    }
    __syncthreads();

    // ---- proj: 8 waves, wave = (pm: 32 rows, pn: 64 cols) ----
    const int pm = wid >> 2, pn = wid & 3;
    f32x4 pacc[2][4];
#pragma unroll
    for (int mt = 0; mt < 2; ++mt)
#pragma unroll
        for (int nt = 0; nt < 4; ++nt) pacc[mt][nt] = zf;

#pragma unroll
    for (int kc = 0; kc < 8; ++kc) {
        bf16x8 a[2];
#pragma unroll
        for (int mt = 0; mt < 2; ++mt) {
            int row = 32 * pm + 16 * mt + li; if (row > 48) row = 48;
            a[mt] = ld8_lds(cb + row * 260 + kc * 32 + q4 * 8);
        }
#pragma unroll
        for (int nt = 0; nt < 4; ++nt) {
            int o = 64 * pn + 16 * nt + li;
            bf16x8 bb = ld8_gb(wpb + (size_t)o * 256 + kc * 32 + q4 * 8);
#pragma unroll
            for (int mt = 0; mt < 2; ++mt)
                pacc[mt][nt] = mfma16(a[mt], bb, pacc[mt][nt]);
        }
    }

    // ---- epilogue: bias + direct fp32 scatter (un-window + roll-back) ----
#pragma unroll
    for (int nt = 0; nt < 4; ++nt) {
        int o = 64 * pn + 16 * nt + li;
        float bias = pbias[o];
#pragma unroll
        for (int mt = 0; mt < 2; ++mt)
#pragma unroll
            for (int reg = 0; reg < 4; ++reg) {
                int n = 32 * pm + 16 * mt + 4 * q4 + reg;
                if (n < 49) {
                    int i = n / 7, j = n - 7 * i;
                    int r = wh * 7 + i + 3;  if (r >= 56) r -= 56;
                    int cc = ww * 7 + j + 3; if (cc >= 56) cc -= 56;
                    out[(((size_t)(b * 56 + r) * 56 + cc) << 8) + o] =
                        pacc[mt][nt][reg] + bias;
                }
            }
    }
}

extern "C" void kernel_launch(void* const* d_in, const int* in_sizes, int n_in,
                              void* d_out, int out_size, void* d_ws, size_t ws_size,
                              hipStream_t stream) {
    const float* x    = (const float*)d_in[0];
    const float* wqkv = (const float*)d_in[1];
    const float* bqkv = (const float*)d_in[2];
    const float* wp   = (const float*)d_in[3];
    const float* pb   = (const float*)d_in[4];
    const float* btab = (const float*)d_in[5];
    float* out = (float*)d_out;

    __bf16* wbuf = (__bf16*)d_ws;            // 262,144 bf16 = 512 KB
    k_w2bf<<<1024, 256, 0, stream>>>(wqkv, wp, wbuf);
    k_swin<<<2048, 512, 0, stream>>>(x, wbuf, bqkv, btab,
                                     wbuf + 196608, pb, out);
}